// Round 2
// baseline (439.197 us; speedup 1.0000x reference)
//
#include <hip/hip_runtime.h>

#define N_IN   16384
#define N_OUT  16384
#define KSZ    9
#define CIN    32
#define COUT   32
#define BC     64          // B*C_IN
#define NSEG   (KSZ * N_OUT)   // 147456 = 576 * 256
#define NBLK   576

// ---------------------------------------------------------------------------
// xq[in][bc] = x[bc][in] * qw[in]   (transpose + quadrature scale)
__global__ void k_xq(const float* __restrict__ x, const float* __restrict__ qw,
                     float* __restrict__ xq) {
    __shared__ float tile[64 * 65];
    const int in0 = blockIdx.x * 64;
    const int tid = threadIdx.x;
#pragma unroll
    for (int i = 0; i < 16; ++i) {
        int idx = tid + i * 256;
        int bcl = idx >> 6, inl = idx & 63;
        tile[bcl * 65 + inl] = x[bcl * N_IN + in0 + inl];
    }
    __syncthreads();
#pragma unroll
    for (int i = 0; i < 16; ++i) {
        int idx = tid + i * 256;
        int inl = idx >> 6, bcl = idx & 63;
        xq[(size_t)(in0 + inl) * BC + bcl] = tile[bcl * 65 + inl] * qw[in0 + inl];
    }
}

// ---------------------------------------------------------------------------
// weight transpose: wT[((k*8 + o/4)*32 + c)*4 + o%4] = w[(o*32+c)*9+k]
// -> per (k, wave, c) the 4 o-values are 16 consecutive floats (s_load friendly)
__global__ void k_wt(const float* __restrict__ w, float* __restrict__ wT) {
    int i = blockIdx.x * 256 + threadIdx.x;
    if (i < COUT * CIN * KSZ) {
        int o = i / (CIN * KSZ);
        int r = i - o * (CIN * KSZ);
        int c = r / KSZ;
        int k = r - c * KSZ;
        wT[((k * 8 + (o >> 2)) * 32 + c) * 4 + (o & 3)] = w[i];
    }
}

// ---------------------------------------------------------------------------
// histogram of segment ids
__global__ void k_hist(const int* __restrict__ ik, const int* __restrict__ io,
                       int* __restrict__ counts, int nnz) {
    int e = blockIdx.x * 256 + threadIdx.x;
    if (e < nnz) atomicAdd(&counts[ik[e] * N_OUT + io[e]], 1);
}

// block-local exclusive scan of 256 counts; writes local-excl + block sum
__global__ void k_scan1(const int* __restrict__ counts, int* __restrict__ local,
                        int* __restrict__ blksum) {
    __shared__ int sd[256];
    int t = threadIdx.x, b = blockIdx.x;
    int v = counts[b * 256 + t];
    sd[t] = v;
    __syncthreads();
    for (int off = 1; off < 256; off <<= 1) {
        int u = (t >= off) ? sd[t - off] : 0;
        __syncthreads();
        sd[t] += u;
        __syncthreads();
    }
    local[b * 256 + t] = sd[t] - v;
    if (t == 255) blksum[b] = sd[t];
}

// scan of the 576 block sums (single block of 576 threads)
__global__ void k_scan2(const int* __restrict__ blksum, int* __restrict__ blkoff) {
    __shared__ int sd[NBLK];
    int t = threadIdx.x;
    int v = blksum[t];
    sd[t] = v;
    __syncthreads();
    for (int off = 1; off < NBLK; off <<= 1) {
        int u = (t >= off) ? sd[t - off] : 0;
        __syncthreads();
        sd[t] += u;
        __syncthreads();
    }
    blkoff[t] = sd[t] - v;
}

// add block offsets; produce offsets[] and a second cursor[] copy
__global__ void k_scan3(int* __restrict__ offsets, int* __restrict__ cursor,
                        const int* __restrict__ blkoff, int nnz) {
    int i = blockIdx.x * 256 + threadIdx.x;
    int v = offsets[i] + blkoff[i >> 8];
    offsets[i] = v;
    cursor[i] = v;
    if (i == 0) offsets[NSEG] = nnz;
}

// scatter entries into segment-sorted order as (val, in_idx) pairs
__global__ void k_reorder(const float* __restrict__ vals, const int* __restrict__ ik,
                          const int* __restrict__ io, const int* __restrict__ ii,
                          int* __restrict__ cursor, float2* __restrict__ siv, int nnz) {
    int e = blockIdx.x * 256 + threadIdx.x;
    if (e >= nnz) return;
    int seg = ik[e] * N_OUT + io[e];
    int pos = atomicAdd(&cursor[seg], 1);
    siv[pos] = make_float2(vals[e], __int_as_float(ii[e]));
}

// ---------------------------------------------------------------------------
// fused gather + einsum.
// Block: 64 n-values, 512 threads (8 waves). lane = n-local; wave = o-group (4 o).
// Loop over 3 k-chunks of 3: gather segments into LDS, then accumulate.
#define TN 64
#define KCH 3
__global__ __launch_bounds__(512) void k_main(
        const float* __restrict__ xq, const float2* __restrict__ siv,
        const int* __restrict__ offsets, const float* __restrict__ wT,
        const float* __restrict__ bias, float* __restrict__ out) {
    __shared__ float sxk[KCH * TN * 68];   // [kk][nl][bc], row stride 68 (16B-aligned)
    const int tid  = threadIdx.x;
    const int lane = tid & 63;
    const int wv   = __builtin_amdgcn_readfirstlane(tid >> 6);  // 0..7, wave-uniform
    const int n0   = blockIdx.x * TN;

    float acc[4][2] = {{0.f, 0.f}, {0.f, 0.f}, {0.f, 0.f}, {0.f, 0.f}};

    for (int kc = 0; kc < KSZ / KCH; ++kc) {
        // ---- gather phase: 192 segments, wave-strided
        for (int s = wv; s < KCH * TN; s += 8) {
            int kk = s >> 6;
            int nl = s & 63;
            int gseg = (kc * KCH + kk) * N_OUT + n0 + nl;
            int e0 = offsets[gseg];
            int e1 = offsets[gseg + 1];
            float a = 0.f;
            for (int e = e0; e < e1; ++e) {
                float2 iv = siv[e];                       // uniform -> s_load
                int in = __float_as_int(iv.y);
                a += xq[(size_t)in * BC + lane] * iv.x;   // coalesced 256B
            }
            sxk[(kk * TN + nl) * 68 + lane] = a;
        }
        __syncthreads();
        // ---- einsum phase
        for (int kk = 0; kk < KCH; ++kk) {
            int k = kc * KCH + kk;
            const float* xr = &sxk[(kk * TN + lane) * 68];
#pragma unroll
            for (int c4 = 0; c4 < 8; ++c4) {
                int c = c4 * 4;
                float4 x0 = *(const float4*)&xr[c];        // b=0, c..c+3
                float4 x1 = *(const float4*)&xr[32 + c];   // b=1
                const float* wp = &wT[((k * 8 + wv) * 32 + c) * 4];  // uniform -> s_load
#pragma unroll
                for (int cc = 0; cc < 4; ++cc) {
                    float xa = (&x0.x)[cc];
                    float xb = (&x1.x)[cc];
#pragma unroll
                    for (int j = 0; j < 4; ++j) {
                        float wval = wp[cc * 4 + j];
                        acc[j][0] += xa * wval;
                        acc[j][1] += xb * wval;
                    }
                }
            }
        }
        __syncthreads();
    }
#pragma unroll
    for (int j = 0; j < 4; ++j) {
        int o = wv * 4 + j;
        float bb = bias[o];
        out[(size_t)(0 * COUT + o) * N_OUT + n0 + lane] = acc[j][0] + bb;
        out[(size_t)(1 * COUT + o) * N_OUT + n0 + lane] = acc[j][1] + bb;
    }
}

// ---------------------------------------------------------------------------
extern "C" void kernel_launch(void* const* d_in, const int* in_sizes, int n_in,
                              void* d_out, int out_size, void* d_ws, size_t ws_size,
                              hipStream_t stream) {
    const float* x    = (const float*)d_in[0];
    const float* qw   = (const float*)d_in[1];
    const float* vals = (const float*)d_in[2];
    const float* w    = (const float*)d_in[3];
    const float* bias = (const float*)d_in[4];
    const int*   ik   = (const int*)d_in[5];
    const int*   io   = (const int*)d_in[6];
    const int*   ii   = (const int*)d_in[7];
    const int    nnz  = in_sizes[2];

    char* ws = (char*)d_ws;
    float* xq      = (float*)ws;                       ws += (size_t)N_IN * BC * 4;      // 4 MB
    int*   counts  = (int*)ws;                         ws += (size_t)NSEG * 4;           // 576 KB
    int*   offsets = (int*)ws;                         ws += (size_t)(NSEG + 4) * 4;
    int*   cursor  = (int*)ws;                         ws += (size_t)NSEG * 4;
    int*   blksum  = (int*)ws;                         ws += (size_t)NBLK * 4;
    int*   blkoff  = (int*)ws;                         ws += (size_t)NBLK * 4;
    float* wT      = (float*)ws;                       ws += (size_t)COUT * CIN * KSZ * 4;
    float2* siv    = (float2*)ws;                      ws += (size_t)nnz * 8;            // 12 MB

    hipMemsetAsync(counts, 0, (size_t)NSEG * 4, stream);
    k_xq <<<N_IN / 64, 256, 0, stream>>>(x, qw, xq);
    k_wt <<<(COUT * CIN * KSZ + 255) / 256, 256, 0, stream>>>(w, wT);
    k_hist<<<(nnz + 255) / 256, 256, 0, stream>>>(ik, io, counts, nnz);
    k_scan1<<<NBLK, 256, 0, stream>>>(counts, offsets, blksum);
    k_scan2<<<1, NBLK, 0, stream>>>(blksum, blkoff);
    k_scan3<<<NSEG / 256, 256, 0, stream>>>(offsets, cursor, blkoff, nnz);
    k_reorder<<<(nnz + 255) / 256, 256, 0, stream>>>(vals, ik, io, ii, cursor, siv, nnz);
    k_main<<<N_OUT / TN, 512, 0, stream>>>(xq, siv, offsets, wT, bias, (float*)d_out);
}

// Round 3
// 324.416 us; speedup vs baseline: 1.3538x; 1.3538x over previous
//
#include <hip/hip_runtime.h>

#define N_IN   16384
#define N_OUT  16384
#define KSZ    9
#define CIN    32
#define COUT   32
#define BC     64              // B*C_IN
#define NSEG   (KSZ * N_OUT)   // 147456 = 576 * 256
#define NBLK   576

// ---------------------------------------------------------------------------
// xq[in][bc] = x[bc][in] * qw[in]   (transpose + quadrature scale)
__global__ void k_xq(const float* __restrict__ x, const float* __restrict__ qw,
                     float* __restrict__ xq) {
    __shared__ float tile[64 * 65];
    const int in0 = blockIdx.x * 64;
    const int tid = threadIdx.x;
#pragma unroll
    for (int i = 0; i < 16; ++i) {
        int idx = tid + i * 256;
        int bcl = idx >> 6, inl = idx & 63;
        tile[bcl * 65 + inl] = x[bcl * N_IN + in0 + inl];
    }
    __syncthreads();
#pragma unroll
    for (int i = 0; i < 16; ++i) {
        int idx = tid + i * 256;
        int inl = idx >> 6, bcl = idx & 63;
        xq[(size_t)(in0 + inl) * BC + bcl] = tile[bcl * 65 + inl] * qw[in0 + inl];
    }
}

// ---------------------------------------------------------------------------
// weight transpose: wT[((k*8 + g)*32 + c)*4 + j] = w[((g*4+j)*32 + c)*9 + k]
__global__ void k_wt(const float* __restrict__ w, float* __restrict__ wT) {
    int i = blockIdx.x * 256 + threadIdx.x;
    if (i < COUT * CIN * KSZ) {
        int o = i / (CIN * KSZ);
        int r = i - o * (CIN * KSZ);
        int c = r / KSZ;
        int k = r - c * KSZ;
        wT[((k * 8 + (o >> 2)) * 32 + c) * 4 + (o & 3)] = w[i];
    }
}

// ---------------------------------------------------------------------------
__global__ void k_hist(const int* __restrict__ ik, const int* __restrict__ io,
                       int* __restrict__ counts, int nnz) {
    int e = blockIdx.x * 256 + threadIdx.x;
    if (e < nnz) atomicAdd(&counts[ik[e] * N_OUT + io[e]], 1);
}

__global__ void k_scan1(const int* __restrict__ counts, int* __restrict__ local,
                        int* __restrict__ blksum) {
    __shared__ int sd[256];
    int t = threadIdx.x, b = blockIdx.x;
    int v = counts[b * 256 + t];
    sd[t] = v;
    __syncthreads();
    for (int off = 1; off < 256; off <<= 1) {
        int u = (t >= off) ? sd[t - off] : 0;
        __syncthreads();
        sd[t] += u;
        __syncthreads();
    }
    local[b * 256 + t] = sd[t] - v;
    if (t == 255) blksum[b] = sd[t];
}

__global__ void k_scan2(const int* __restrict__ blksum, int* __restrict__ blkoff) {
    __shared__ int sd[NBLK];
    int t = threadIdx.x;
    int v = blksum[t];
    sd[t] = v;
    __syncthreads();
    for (int off = 1; off < NBLK; off <<= 1) {
        int u = (t >= off) ? sd[t - off] : 0;
        __syncthreads();
        sd[t] += u;
        __syncthreads();
    }
    blkoff[t] = sd[t] - v;
}

__global__ void k_scan3(int* __restrict__ offsets, int* __restrict__ cursor,
                        const int* __restrict__ blkoff, int nnz) {
    int i = blockIdx.x * 256 + threadIdx.x;
    int v = offsets[i] + blkoff[i >> 8];
    offsets[i] = v;
    cursor[i] = v;
    if (i == 0) offsets[NSEG] = nnz;
}

__global__ void k_reorder(const float* __restrict__ vals, const int* __restrict__ ik,
                          const int* __restrict__ io, const int* __restrict__ ii,
                          int* __restrict__ cursor, float2* __restrict__ siv, int nnz) {
    int e = blockIdx.x * 256 + threadIdx.x;
    if (e >= nnz) return;
    int seg = ik[e] * N_OUT + io[e];
    int pos = atomicAdd(&cursor[seg], 1);
    siv[pos] = make_float2(vals[e], __int_as_float(ii[e]));
}

// ---------------------------------------------------------------------------
// gather: one wave per segment (k, n). lane = bc. Writes xk[seg][bc].
__global__ __launch_bounds__(256) void k_gather(
        const float* __restrict__ xq, const float2* __restrict__ siv,
        const int* __restrict__ offsets, float* __restrict__ xk) {
    const int lane = threadIdx.x & 63;
    int seg = blockIdx.x * 4 + (threadIdx.x >> 6);
    seg = __builtin_amdgcn_readfirstlane(seg);
    const int e0 = offsets[seg];
    const int e1 = offsets[seg + 1];
    float a0 = 0.f, a1 = 0.f;
    int e = e0;
    for (; e + 1 < e1; e += 2) {
        float2 v0 = siv[e];
        float2 v1 = siv[e + 1];
        a0 += xq[(size_t)__float_as_int(v0.y) * BC + lane] * v0.x;
        a1 += xq[(size_t)__float_as_int(v1.y) * BC + lane] * v1.x;
    }
    if (e < e1) {
        float2 v = siv[e];
        a0 += xq[(size_t)__float_as_int(v.y) * BC + lane] * v.x;
    }
    xk[(size_t)seg * BC + lane] = a0 + a1;
}

// ---------------------------------------------------------------------------
// einsum: out[b][o][n] = sum_{k,c} xk[k][n][b*32+c] * w[o][c][k] + bias[o]
// 512 thr: lane = (h=b)*32 + nl ; wave wv = o-group (4 o). Tile stride 67
// (odd) -> conflict-free ds_read_b32 across nl; h-alias is 2-way (free).
#define TN2 32
__global__ __launch_bounds__(512) void k_einsum(
        const float* __restrict__ xk, const float* __restrict__ wT,
        const float* __restrict__ bias, float* __restrict__ out) {
    __shared__ float sxk[KSZ * TN2 * 67];
    const int tid = threadIdx.x;
    const int n0  = blockIdx.x * TN2;

    for (int i = tid; i < KSZ * TN2 * 16; i += 512) {
        int row = i >> 4;            // k*32 + nl
        int c4  = (i & 15) * 4;
        int k = row >> 5, nl = row & 31;
        const float4 v = *(const float4*)&xk[((size_t)k * N_OUT + n0 + nl) * BC + c4];
        float* d = &sxk[row * 67 + c4];
        d[0] = v.x; d[1] = v.y; d[2] = v.z; d[3] = v.w;
    }
    __syncthreads();

    const int lane = tid & 63;
    const int h    = lane >> 5;      // b
    const int nl   = lane & 31;
    const int wv   = __builtin_amdgcn_readfirstlane(tid >> 6);  // o-group 0..7
    float acc[4] = {0.f, 0.f, 0.f, 0.f};
    for (int k = 0; k < KSZ; ++k) {
        const float* xr = &sxk[(k * TN2 + nl) * 67 + h * 32];
        const float* wp = &wT[(k * 8 + wv) * 128];               // uniform -> s_load
#pragma unroll
        for (int c = 0; c < 32; ++c) {
            float xv = xr[c];
#pragma unroll
            for (int j = 0; j < 4; ++j) acc[j] += xv * wp[c * 4 + j];
        }
    }
#pragma unroll
    for (int j = 0; j < 4; ++j) {
        int o = wv * 4 + j;
        out[((size_t)h * COUT + o) * N_OUT + n0 + nl] = acc[j] + bias[o];
    }
}

// ---------------------------------------------------------------------------
extern "C" void kernel_launch(void* const* d_in, const int* in_sizes, int n_in,
                              void* d_out, int out_size, void* d_ws, size_t ws_size,
                              hipStream_t stream) {
    const float* x    = (const float*)d_in[0];
    const float* qw   = (const float*)d_in[1];
    const float* vals = (const float*)d_in[2];
    const float* w    = (const float*)d_in[3];
    const float* bias = (const float*)d_in[4];
    const int*   ik   = (const int*)d_in[5];
    const int*   io   = (const int*)d_in[6];
    const int*   ii   = (const int*)d_in[7];
    const int    nnz  = in_sizes[2];

    char* ws = (char*)d_ws;
    float*  xq      = (float*)ws;   ws += (size_t)N_IN * BC * 4;          // 4 MB
    float*  xk      = (float*)ws;   ws += (size_t)NSEG * BC * 4;          // 37.75 MB
    float2* siv     = (float2*)ws;  ws += (size_t)nnz * 8;                // 12 MB
    int*    counts  = (int*)ws;     ws += (size_t)NSEG * 4;
    int*    offsets = (int*)ws;     ws += (size_t)(NSEG + 4) * 4;
    int*    cursor  = (int*)ws;     ws += (size_t)NSEG * 4;
    int*    blksum  = (int*)ws;     ws += (size_t)NBLK * 4;
    int*    blkoff  = (int*)ws;     ws += (size_t)NBLK * 4;
    float*  wT      = (float*)ws;   ws += (size_t)COUT * CIN * KSZ * 4;

    hipMemsetAsync(counts, 0, (size_t)NSEG * 4, stream);
    k_xq <<<N_IN / 64, 256, 0, stream>>>(x, qw, xq);
    k_wt <<<(COUT * CIN * KSZ + 255) / 256, 256, 0, stream>>>(w, wT);
    k_hist<<<(nnz + 255) / 256, 256, 0, stream>>>(ik, io, counts, nnz);
    k_scan1<<<NBLK, 256, 0, stream>>>(counts, offsets, blksum);
    k_scan2<<<1, NBLK, 0, stream>>>(blksum, blkoff);
    k_scan3<<<NSEG / 256, 256, 0, stream>>>(offsets, cursor, blkoff, nnz);
    k_reorder<<<(nnz + 255) / 256, 256, 0, stream>>>(vals, ik, io, ii, cursor, siv, nnz);
    k_gather<<<NSEG / 4, 256, 0, stream>>>(xq, siv, offsets, xk);
    k_einsum<<<N_OUT / TN2, 512, 0, stream>>>(xk, wT, bias, (float*)d_out);
}